// Round 10
// baseline (1353.346 us; speedup 1.0000x reference)
//
#include <hip/hip_runtime.h>

#define N_USERS 100000
#define N_ITEMS 30000
#define NE      1000000
#define D       128
#define CHUNK   4096
#define HCHUNK  8192
#define STAGE_B 7424
#define SH_U    9    // 512 users/bucket  -> 196 buckets
#define SH_I    7    // 128 items/bucket  -> 235 buckets
#define NB_U    ((N_USERS + (1 << SH_U) - 1) >> SH_U)
#define NB_I    ((N_ITEMS + (1 << SH_I) - 1) >> SH_I)

__device__ __forceinline__ unsigned f2bf(float f) {
    unsigned u = __float_as_uint(f);
    return (u + 0x7fffu + ((u >> 16) & 1u)) >> 16;   // RNE, no NaN expected
}
__device__ __forceinline__ float bflo(unsigned v) { return __uint_as_float(v << 16); }
__device__ __forceinline__ float bfhi(unsigned v) { return __uint_as_float(v & 0xffff0000u); }

// ---------------- bucket histograms (LDS-aggregated, tiny global atomics) ----------
struct HistArgs { const int* dst[6]; int shift[6]; int* bh; };

__global__ __launch_bounds__(256) void k_bhist(HistArgs a) {
    __shared__ int h[256];
    const int l = blockIdx.y;
    const int* __restrict__ dst = a.dst[l];
    const int sh = a.shift[l];
    const int t = threadIdx.x;
    h[t] = 0;
    __syncthreads();
    const int e0 = blockIdx.x * HCHUNK;
    const int e1 = min(e0 + HCHUNK, NE);
    for (int e = e0 + t; e < e1; e += 256) atomicAdd(&h[dst[e] >> sh], 1);
    __syncthreads();
    if (h[t]) atomicAdd(&a.bh[l * 256 + t], h[t]);
}

// ---------------- bucket-count scan: bucket starts + pass-A cursors ----------------
__global__ void k_scanB(const int* __restrict__ bh, int* __restrict__ bstart,
                        int* __restrict__ gcur) {
    __shared__ int lds[256];
    const int l = blockIdx.x, t = threadIdx.x;
    const int x = bh[l * 256 + t];
    lds[t] = x;
    __syncthreads();
    for (int o = 1; o < 256; o <<= 1) {
        int add = (t >= o) ? lds[t - o] : 0;
        __syncthreads();
        lds[t] += add;
        __syncthreads();
    }
    const int excl = lds[t] - x;
    bstart[l * 257 + t] = excl;
    gcur[l * 256 + t] = excl;
    if (t == 255) bstart[l * 257 + 256] = lds[t];
}

// ---------------- pass A: bucket-binned scatter (no coefficients yet) --------------
struct BinList { const int* dst; const int* srcp; const float* w; int shift; int* gcur; int2* tmp; };
struct BinArgs { BinList l[6]; };

__global__ __launch_bounds__(256) void k_binA(BinArgs ba) {
    const BinList L = ba.l[blockIdx.y];
    __shared__ int2 stg[CHUNK];
    __shared__ unsigned char bkt[CHUNK];
    __shared__ int hist[256], sbase[256], scur[256], gbase[256];
    const int t = threadIdx.x;
    const int e0 = blockIdx.x * CHUNK;
    const int ccnt = min(CHUNK, NE - e0);
    hist[t] = 0;
    __syncthreads();
#pragma unroll
    for (int j = 0; j < CHUNK / 256; ++j) {
        const int e = e0 + j * 256 + t;
        if (e < NE) atomicAdd(&hist[L.dst[e] >> L.shift], 1);
    }
    __syncthreads();
    {
        const int x = hist[t];
        sbase[t] = x;
        __syncthreads();
        for (int o = 1; o < 256; o <<= 1) {
            int add = (t >= o) ? sbase[t - o] : 0;
            __syncthreads();
            sbase[t] += add;
            __syncthreads();
        }
        const int excl = sbase[t] - x;
        __syncthreads();
        sbase[t] = excl;
        scur[t] = excl;
        gbase[t] = (x > 0) ? atomicAdd(&L.gcur[t], x) : 0;
    }
    __syncthreads();
#pragma unroll
    for (int j = 0; j < CHUNK / 256; ++j) {
        const int e = e0 + j * 256 + t;
        if (e < NE) {
            const int d = L.dst[e], s = L.srcp[e];
            const int b = d >> L.shift;
            const int p = atomicAdd(&scur[b], 1);
            stg[p] = make_int2(((d & ((1 << L.shift) - 1)) << 17) | s,
                               L.w ? __float_as_int(L.w[e]) : 0);
            bkt[p] = (unsigned char)b;
        }
    }
    __syncthreads();
    for (int i = t; i < ccnt; i += 256) {
        const int b = bkt[i];
        L.tmp[gbase[b] + (i - sbase[b])] = stg[i];
    }
}

// ---------------- per-bucket degree count + row starts (coalesced writes) ----------
struct DegArgs {
    const int2* tmp[6];
    const int* bstart;       // [6*257]
    int* rs[6];
    float* rdeg[6];
    int shift[6]; int n[6]; int bofs[7];
};

__global__ __launch_bounds__(256) void k_bdeg(DegArgs a) {
    __shared__ int cnt[512];
    __shared__ int lds[256];
    int l = 0;
    while ((int)blockIdx.x >= a.bofs[l + 1]) ++l;
    const int b = blockIdx.x - a.bofs[l];
    const int sh = a.shift[l], n = a.n[l];
    const int node0 = b << sh;
    const int node1 = min(node0 + (1 << sh), n);
    const int nn = node1 - node0;
    const int bs = a.bstart[l * 257 + b], be = a.bstart[l * 257 + b + 1];
    const int t = threadIdx.x;
    cnt[t] = 0; cnt[t + 256] = 0;
    __syncthreads();
    const int2* __restrict__ tmp = a.tmp[l];
    for (int i = bs + t; i < be; i += 256) atomicAdd(&cnt[((unsigned)tmp[i].x) >> 17], 1);
    __syncthreads();
    const int c0 = cnt[2 * t], c1 = cnt[2 * t + 1];
    lds[t] = c0 + c1;
    __syncthreads();
    for (int o = 1; o < 256; o <<= 1) {
        int add = (t >= o) ? lds[t - o] : 0;
        __syncthreads();
        lds[t] += add;
        __syncthreads();
    }
    const int ep = lds[t] - (c0 + c1);   // exclusive prefix at element 2t
    int* __restrict__ rs = a.rs[l];
    float* __restrict__ rd = a.rdeg[l];
    if (2 * t < nn) {
        rs[node0 + 2 * t] = bs + ep;
        rd[node0 + 2 * t] = rsqrtf((float)max(c0, 1));
    }
    if (2 * t + 1 < nn) {
        rs[node0 + 2 * t + 1] = bs + ep + c0;
        rd[node0 + 2 * t + 1] = rsqrtf((float)max(c1, 1));
    }
    if (t == 0) rs[node1] = be;
}

// ---------------- pass B: coefficient compute + exact row sort, coalesced ----------
// payload written as (src_byte_offset = src*256, coef)
struct SortArgs {
    const int2* tmp[6]; int2* outp[6];
    const int* rs[6];
    const float* rdD[6]; const float* rdS[6];
    const int* bstart;
    int shift[6]; int n[6]; int mode[6];   // mode 0: c  1: 0.5*w*c  2: 0.5*c
    int bofs[7];
};

__global__ __launch_bounds__(256) void k_binB(SortArgs a) {
    __shared__ int2 stg[STAGE_B];
    __shared__ int lcur[512];
    __shared__ float rdl[512];
    int l = 0;
    while ((int)blockIdx.x >= a.bofs[l + 1]) ++l;
    const int b = blockIdx.x - a.bofs[l];
    const int sh = a.shift[l], n = a.n[l], mode = a.mode[l];
    const int node0 = b << sh;
    const int node1 = min(node0 + (1 << sh), n);
    const int nn = node1 - node0;
    const int bs = a.bstart[l * 257 + b], be = a.bstart[l * 257 + b + 1], cnt = be - bs;
    const int t = threadIdx.x;
    const int* __restrict__ rs = a.rs[l];
    const float* __restrict__ rdD = a.rdD[l];
    for (int k = t; k < nn; k += 256) {
        lcur[k] = rs[node0 + k] - bs;
        rdl[k] = rdD[node0 + k];
    }
    __syncthreads();
    const int2* __restrict__ tmp = a.tmp[l];
    int2* __restrict__ outp = a.outp[l];
    const float* __restrict__ rdS = a.rdS[l];
    if (cnt <= STAGE_B) {
        for (int i = bs + t; i < be; i += 256) {
            const int2 v = tmp[i];
            const int dl = ((unsigned)v.x) >> 17, src = v.x & 0x1FFFF;
            float c = rdl[dl] * rdS[src];
            if (mode == 1) c *= 0.5f * __int_as_float(v.y);
            else if (mode == 2) c *= 0.5f;
            const int slot = atomicAdd(&lcur[dl], 1);
            stg[slot] = make_int2(src << 8, __float_as_int(c));
        }
        __syncthreads();
        for (int i = t; i < cnt; i += 256) outp[bs + i] = stg[i];
    } else {  // statistically unreachable fallback
        for (int i = bs + t; i < be; i += 256) {
            const int2 v = tmp[i];
            const int dl = ((unsigned)v.x) >> 17, src = v.x & 0x1FFFF;
            float c = rdl[dl] * rdS[src];
            if (mode == 1) c *= 0.5f * __int_as_float(v.y);
            else if (mode == 2) c *= 0.5f;
            const int slot = atomicAdd(&lcur[dl], 1);
            outp[bs + slot] = make_int2(src << 8, __float_as_int(c));
        }
    }
}

// ---------------- f32 -> bf16 convert (4 floats / thread) ----------------
__global__ void k_tobf16(const float* __restrict__ in, ushort* __restrict__ out, int n4) {
    int i = blockIdx.x * blockDim.x + threadIdx.x;
    if (i >= n4) return;
    float4 v = ((const float4*)in)[i];
    ((uint2*)out)[i] = make_uint2((f2bf(v.y) << 16) | f2bf(v.x),
                                  (f2bf(v.w) << 16) | f2bf(v.z));
}

// ---------------- D-sliced conv: LPR lanes per row, slice of the feature dim -------
// Each pass gathers only slice_byte..slice_byte+LPR*4 of every 256B row, so the
// per-dispatch gather working set is table_size * LPR/64 (L2-resident by design).
struct ConvSliceArgs {
    const ushort* x;
    const int*  rs1; const int2* p1;
    const int*  rs2; const int2* p2;
    const ushort* base;
    float*  outf; float* outf2;
    ushort* outb;
    int n;
    int slice_byte;    // 0,64,128,192 — byte offset within the 256B bf16 row
};

template<int LPR>
__device__ __forceinline__ void accum_slice(const char* __restrict__ xs,
                                            const int* __restrict__ rs,
                                            const int2* __restrict__ p,
                                            int row, int lane,
                                            float& ax, float& ay) {
    const int j0 = rs[row], j1 = rs[row + 1];
    const int li = lane & (LPR - 1);
    const int gb = lane - li;            // group base lane
    const int lib = li * 4;
    for (int jb = j0; jb < j1; jb += LPR) {
        int2 mp = make_int2(0, 0);
        if (jb + li < j1) mp = p[jb + li];
        const int cnt = min(LPR, j1 - jb);
        int t = 0;
        for (; t + 8 <= cnt; t += 8) {
            unsigned v[8]; float c[8];
#pragma unroll
            for (int k = 0; k < 8; ++k) {
                const int sl = gb + t + k;
                const int so = __shfl(mp.x, sl, 64);
                c[k] = __int_as_float(__shfl(mp.y, sl, 64));
                v[k] = *(const unsigned*)(xs + so + lib);
            }
#pragma unroll
            for (int k = 0; k < 8; ++k) {
                ax = fmaf(c[k], bflo(v[k]), ax);
                ay = fmaf(c[k], bfhi(v[k]), ay);
            }
        }
        if (t + 4 <= cnt) {
            unsigned v[4]; float c[4];
#pragma unroll
            for (int k = 0; k < 4; ++k) {
                const int sl = gb + t + k;
                const int so = __shfl(mp.x, sl, 64);
                c[k] = __int_as_float(__shfl(mp.y, sl, 64));
                v[k] = *(const unsigned*)(xs + so + lib);
            }
#pragma unroll
            for (int k = 0; k < 4; ++k) {
                ax = fmaf(c[k], bflo(v[k]), ax);
                ay = fmaf(c[k], bfhi(v[k]), ay);
            }
            t += 4;
        }
        for (; t < cnt; ++t) {
            const int sl = gb + t;
            const int so = __shfl(mp.x, sl, 64);
            const float c = __int_as_float(__shfl(mp.y, sl, 64));
            const unsigned v = *(const unsigned*)(xs + so + lib);
            ax = fmaf(c, bflo(v), ax);
            ay = fmaf(c, bfhi(v), ay);
        }
    }
}

template<int LPR>
__global__ __launch_bounds__(256) void k_convS(ConvSliceArgs A) {
    constexpr int RPW = 64 / LPR;
    // bijective XCD swizzle (grid padded to a multiple of 8)
    const int q = (int)gridDim.x >> 3;
    const int bid = (int)blockIdx.x;
    const int rb = (bid & 7) * q + (bid >> 3);
    const int wid = rb * 4 + (int)(threadIdx.x >> 6);
    const int lane = threadIdx.x & 63;
    const int g = lane / LPR;
    const int row = wid * RPW + g;
    if (row >= A.n) return;
    const int li = lane & (LPR - 1);
    const size_t roff = (size_t)row * D + (A.slice_byte >> 1) + li * 2;
    float ax = 0.f, ay = 0.f;
    if (A.base) {
        const unsigned b = *(const unsigned*)(A.base + roff);
        ax = bflo(b); ay = bfhi(b);
    }
    const char* xs = (const char*)A.x + A.slice_byte;
    accum_slice<LPR>(xs, A.rs1, A.p1, row, lane, ax, ay);
    if (A.rs2) accum_slice<LPR>(xs, A.rs2, A.p2, row, lane, ax, ay);
    if (A.outf)  *(float2*)(A.outf  + roff) = make_float2(ax, ay);
    if (A.outf2) *(float2*)(A.outf2 + roff) = make_float2(ax, ay);
    if (A.outb)  *(unsigned*)(A.outb + roff) = (f2bf(ay) << 16) | f2bf(ax);
}

extern "C" void kernel_launch(void* const* d_in, const int* in_sizes, int n_in,
                              void* d_out, int out_size, void* d_ws, size_t ws_size,
                              hipStream_t stream) {
    const float* user_emb = (const float*)d_in[0];
    const float* item_emb = (const float*)d_in[1];
    const float* w_edge   = (const float*)d_in[2];
    const int* ou = (const int*)d_in[3];
    const int* oi = (const int*)d_in[4];
    const int* su = (const int*)d_in[5];
    const int* si = (const int*)d_in[6];
    const int* du = (const int*)d_in[7];
    const int* di = (const int*)d_in[8];
    float* out = (float*)d_out;

    const size_t SZ_U = (size_t)N_USERS * D;
    const size_t SZ_I = (size_t)N_ITEMS * D;

    // output slices: (hu, hi, hu, hi, h1u, h1i)
    float* o0 = out;
    float* o1 = o0 + SZ_U;
    float* o2 = o1 + SZ_I;
    float* o3 = o2 + SZ_U;
    float* o4 = o3 + SZ_I;
    float* o5 = o4 + SZ_U;

    // bf16 intermediates live in the o4/o5 slices (dead until loop-2 iter2):
    ushort* tU0 = (ushort*)o4;  ushort* tU1 = tU0 + SZ_U;
    ushort* tI0 = (ushort*)o5;  ushort* tI1 = tI0 + SZ_I;

    // ---- workspace carve-out ----
    char* ws = (char*)d_ws;
    size_t off = 0;
    auto alloc = [&](size_t bytes) -> void* {
        void* p = ws + off;
        off = (off + bytes + 255) & ~(size_t)255;
        return p;
    };

    int* rOU = (int*)alloc((N_USERS + 1) * 4);
    int* rOI = (int*)alloc((N_ITEMS + 1) * 4);
    int* rSU = (int*)alloc((N_USERS + 1) * 4);
    int* rSI = (int*)alloc((N_ITEMS + 1) * 4);
    int* rDU = (int*)alloc((N_USERS + 1) * 4);
    int* rDI = (int*)alloc((N_ITEMS + 1) * 4);

    float* rdOU = (float*)alloc(N_USERS * 4);
    float* rdOI = (float*)alloc(N_ITEMS * 4);
    float* rdSU = (float*)alloc(N_USERS * 4);
    float* rdSI = (float*)alloc(N_ITEMS * 4);
    float* rdDU = (float*)alloc(N_USERS * 4);
    float* rdDI = (float*)alloc(N_ITEMS * 4);

    size_t bhBegin = off;
    int* bh     = (int*)alloc(6 * 256 * 4);
    size_t bhEnd = off;
    int* bstart = (int*)alloc(6 * 257 * 4);
    int* gcur   = (int*)alloc(6 * 256 * 4);

    int2* pOU = (int2*)alloc((size_t)NE * 8);
    int2* pOI = (int2*)alloc((size_t)NE * 8);
    int2* pSU = (int2*)alloc((size_t)NE * 8);
    int2* pSI = (int2*)alloc((size_t)NE * 8);
    int2* pDU = (int2*)alloc((size_t)NE * 8);
    int2* pDI = (int2*)alloc((size_t)NE * 8);

    int2* qOU = (int2*)alloc((size_t)NE * 8);   // binned (pass-A) staging
    int2* qOI = (int2*)alloc((size_t)NE * 8);
    int2* qSU = (int2*)alloc((size_t)NE * 8);
    int2* qSI = (int2*)alloc((size_t)NE * 8);
    int2* qDU = (int2*)alloc((size_t)NE * 8);
    int2* qDI = (int2*)alloc((size_t)NE * 8);

    ushort* ebU = (ushort*)alloc(SZ_U * 2);
    ushort* ebI = (ushort*)alloc(SZ_I * 2);
    ushort* fUb = (ushort*)alloc(SZ_U * 2);
    ushort* fIb = (ushort*)alloc(SZ_I * 2);

    // ---- phase 0: zero bucket hist; convert embeddings to bf16 ----
    hipMemsetAsync(ws + bhBegin, 0, bhEnd - bhBegin, stream);
    hipLaunchKernelGGL(k_tobf16, dim3((unsigned)(SZ_U / 4 + 255) / 256), dim3(256), 0, stream,
                       user_emb, ebU, (int)(SZ_U / 4));
    hipLaunchKernelGGL(k_tobf16, dim3((unsigned)(SZ_I / 4 + 255) / 256), dim3(256), 0, stream,
                       item_emb, ebI, (int)(SZ_I / 4));

    // ---- phase 1: bucket histograms + bucket scan ----
    HistArgs ha;
    ha.dst[0] = ou; ha.shift[0] = SH_U;
    ha.dst[1] = oi; ha.shift[1] = SH_I;
    ha.dst[2] = su; ha.shift[2] = SH_U;
    ha.dst[3] = si; ha.shift[3] = SH_I;
    ha.dst[4] = du; ha.shift[4] = SH_U;
    ha.dst[5] = di; ha.shift[5] = SH_I;
    ha.bh = bh;
    hipLaunchKernelGGL(k_bhist, dim3((NE + HCHUNK - 1) / HCHUNK, 6), dim3(256), 0, stream, ha);
    hipLaunchKernelGGL(k_scanB, dim3(6), dim3(256), 0, stream, bh, bstart, gcur);

    // ---- phase 2: pass A (bin by destination bucket) ----
    BinArgs ba;
    ba.l[0] = { ou, oi, nullptr, SH_U, gcur + 0 * 256, qOU };
    ba.l[1] = { oi, ou, nullptr, SH_I, gcur + 1 * 256, qOI };
    ba.l[2] = { su, si, w_edge,  SH_U, gcur + 2 * 256, qSU };
    ba.l[3] = { si, su, nullptr, SH_I, gcur + 3 * 256, qSI };
    ba.l[4] = { du, di, nullptr, SH_U, gcur + 4 * 256, qDU };
    ba.l[5] = { di, du, nullptr, SH_I, gcur + 5 * 256, qDI };
    hipLaunchKernelGGL(k_binA, dim3((NE + CHUNK - 1) / CHUNK, 6), dim3(256), 0, stream, ba);

    int bofs[7];
    {
        int nb[6] = { NB_U, NB_I, NB_U, NB_I, NB_U, NB_I };
        bofs[0] = 0;
        for (int i = 0; i < 6; ++i) bofs[i + 1] = bofs[i] + nb[i];
    }

    // ---- phase 3: per-bucket degrees + row starts ----
    DegArgs da;
    da.tmp[0] = qOU; da.rs[0] = rOU; da.rdeg[0] = rdOU; da.shift[0] = SH_U; da.n[0] = N_USERS;
    da.tmp[1] = qOI; da.rs[1] = rOI; da.rdeg[1] = rdOI; da.shift[1] = SH_I; da.n[1] = N_ITEMS;
    da.tmp[2] = qSU; da.rs[2] = rSU; da.rdeg[2] = rdSU; da.shift[2] = SH_U; da.n[2] = N_USERS;
    da.tmp[3] = qSI; da.rs[3] = rSI; da.rdeg[3] = rdSI; da.shift[3] = SH_I; da.n[3] = N_ITEMS;
    da.tmp[4] = qDU; da.rs[4] = rDU; da.rdeg[4] = rdDU; da.shift[4] = SH_U; da.n[4] = N_USERS;
    da.tmp[5] = qDI; da.rs[5] = rDI; da.rdeg[5] = rdDI; da.shift[5] = SH_I; da.n[5] = N_ITEMS;
    da.bstart = bstart;
    for (int i = 0; i < 7; ++i) da.bofs[i] = bofs[i];
    hipLaunchKernelGGL(k_bdeg, dim3(bofs[6]), dim3(256), 0, stream, da);

    // ---- phase 4: pass B (coefficients + exact row sort, src pre-scaled to bytes) --
    SortArgs so;
    so.tmp[0] = qOU; so.outp[0] = pOU; so.rs[0] = rOU; so.rdD[0] = rdOU; so.rdS[0] = rdOI;
    so.shift[0] = SH_U; so.n[0] = N_USERS; so.mode[0] = 0;
    so.tmp[1] = qOI; so.outp[1] = pOI; so.rs[1] = rOI; so.rdD[1] = rdOI; so.rdS[1] = rdOU;
    so.shift[1] = SH_I; so.n[1] = N_ITEMS; so.mode[1] = 0;
    so.tmp[2] = qSU; so.outp[2] = pSU; so.rs[2] = rSU; so.rdD[2] = rdSU; so.rdS[2] = rdSI;
    so.shift[2] = SH_U; so.n[2] = N_USERS; so.mode[2] = 1;
    so.tmp[3] = qSI; so.outp[3] = pSI; so.rs[3] = rSI; so.rdD[3] = rdSI; so.rdS[3] = rdSU;
    so.shift[3] = SH_I; so.n[3] = N_ITEMS; so.mode[3] = 2;
    so.tmp[4] = qDU; so.outp[4] = pDU; so.rs[4] = rDU; so.rdD[4] = rdDU; so.rdS[4] = rdDI;
    so.shift[4] = SH_U; so.n[4] = N_USERS; so.mode[4] = 0;
    so.tmp[5] = qDI; so.outp[5] = pDI; so.rs[5] = rDI; so.rdD[5] = rdDI; so.rdS[5] = rdDU;
    so.shift[5] = SH_I; so.n[5] = N_ITEMS; so.mode[5] = 0;
    so.bstart = bstart;
    for (int i = 0; i < 7; ++i) so.bofs[i] = bofs[i];
    hipLaunchKernelGGL(k_binB, dim3(bofs[6]), dim3(256), 0, stream, so);

    // ---- sliced conv dispatch helpers ----
    // user-dst convs gather the 7.7MB item table: 2 passes x 128B (3.84MB slice)
    // item-dst convs gather the 25.6MB user table: 4 passes x 64B (6.4MB slice)
    auto convU = [&](const ushort* x, const int* rs1, const int2* p1,
                     const int* rs2, const int2* p2, const ushort* base,
                     float* outf, float* outf2, ushort* outb) {
        const int waves = (N_USERS + 1) / 2;               // RPW=2
        const int nwg = (((waves + 3) / 4) + 7) & ~7;
        for (int s = 0; s < 2; ++s) {
            ConvSliceArgs A{ x, rs1, p1, rs2, p2, base, outf, outf2, outb,
                             N_USERS, s * 128 };
            hipLaunchKernelGGL(HIP_KERNEL_NAME(k_convS<32>), dim3((unsigned)nwg),
                               dim3(256), 0, stream, A);
        }
    };
    auto convI = [&](const ushort* x, const int* rs1, const int2* p1,
                     const int* rs2, const int2* p2, const ushort* base,
                     float* outf, float* outf2, ushort* outb) {
        const int waves = (N_ITEMS + 3) / 4;               // RPW=4
        const int nwg = (((waves + 3) / 4) + 7) & ~7;
        for (int s = 0; s < 4; ++s) {
            ConvSliceArgs A{ x, rs1, p1, rs2, p2, base, outf, outf2, outb,
                             N_ITEMS, s * 64 };
            hipLaunchKernelGGL(HIP_KERNEL_NAME(k_convS<16>), dim3((unsigned)nwg),
                               dim3(256), 0, stream, A);
        }
    };

    // ---- phase 5: loop 1 (3 layers) ----
    convU(ebI, rOU, pOU, rSU, pSU, nullptr, nullptr, nullptr, tU0);
    convI(ebU, rOI, pOI, rSI, pSI, nullptr, nullptr, nullptr, tI0);
    convU(tI0, rOU, pOU, rSU, pSU, nullptr, nullptr, nullptr, tU1);
    convI(tU0, rOI, pOI, rSI, pSI, nullptr, nullptr, nullptr, tI1);
    convU(tI1, rOU, pOU, rSU, pSU, nullptr, o0, o2, tU0);
    convI(tU1, rOI, pOI, rSI, pSI, nullptr, o1, o3, tI0);

    // ---- phase 6: constant seek terms from bf16 finals; coefs include the 0.5 ----
    convU(tI0, rSU, pSU, nullptr, nullptr, nullptr, nullptr, nullptr, fUb);
    convI(tU0, rSI, pSI, nullptr, nullptr, nullptr, nullptr, nullptr, fIb);

    // ---- phase 7: loop 2 (3 layers), dn graph + constant bf16 base ----
    convU(ebI, rDU, pDU, nullptr, nullptr, fUb, nullptr, nullptr, tU1);
    convI(ebU, rDI, pDI, nullptr, nullptr, fIb, nullptr, nullptr, tI1);
    convU(tI1, rDU, pDU, nullptr, nullptr, fUb, nullptr, nullptr, ebU);
    convI(tU1, rDI, pDI, nullptr, nullptr, fIb, nullptr, nullptr, ebI);
    convU(ebI, rDU, pDU, nullptr, nullptr, fUb, o4, nullptr, nullptr);
    convI(ebU, rDI, pDI, nullptr, nullptr, fIb, o5, nullptr, nullptr);
}

// Round 11
// 957.706 us; speedup vs baseline: 1.4131x; 1.4131x over previous
//
#include <hip/hip_runtime.h>

#define N_USERS 100000
#define N_ITEMS 30000
#define NE      1000000
#define D       128
#define CHUNK   4096
#define HCHUNK  8192
#define STAGE_B 7424
#define SH_U    9    // 512 users/bucket  -> 196 buckets
#define SH_I    7    // 128 items/bucket  -> 235 buckets
#define NB_U    ((N_USERS + (1 << SH_U) - 1) >> SH_U)
#define NB_I    ((N_ITEMS + (1 << SH_I) - 1) >> SH_I)

__device__ __forceinline__ unsigned f2bf(float f) {
    unsigned u = __float_as_uint(f);
    return (u + 0x7fffu + ((u >> 16) & 1u)) >> 16;   // RNE, no NaN expected
}
__device__ __forceinline__ float bflo(unsigned v) { return __uint_as_float(v << 16); }
__device__ __forceinline__ float bfhi(unsigned v) { return __uint_as_float(v & 0xffff0000u); }

// ---------------- bucket histograms (LDS-aggregated, tiny global atomics) ----------
struct HistArgs { const int* dst[6]; int shift[6]; int* bh; };

__global__ __launch_bounds__(256) void k_bhist(HistArgs a) {
    __shared__ int h[256];
    const int l = blockIdx.y;
    const int* __restrict__ dst = a.dst[l];
    const int sh = a.shift[l];
    const int t = threadIdx.x;
    h[t] = 0;
    __syncthreads();
    const int e0 = blockIdx.x * HCHUNK;
    const int e1 = min(e0 + HCHUNK, NE);
    for (int e = e0 + t; e < e1; e += 256) atomicAdd(&h[dst[e] >> sh], 1);
    __syncthreads();
    if (h[t]) atomicAdd(&a.bh[l * 256 + t], h[t]);
}

// ---------------- bucket-count scan: bucket starts + pass-A cursors ----------------
__global__ void k_scanB(const int* __restrict__ bh, int* __restrict__ bstart,
                        int* __restrict__ gcur) {
    __shared__ int lds[256];
    const int l = blockIdx.x, t = threadIdx.x;
    const int x = bh[l * 256 + t];
    lds[t] = x;
    __syncthreads();
    for (int o = 1; o < 256; o <<= 1) {
        int add = (t >= o) ? lds[t - o] : 0;
        __syncthreads();
        lds[t] += add;
        __syncthreads();
    }
    const int excl = lds[t] - x;
    bstart[l * 257 + t] = excl;
    gcur[l * 256 + t] = excl;
    if (t == 255) bstart[l * 257 + 256] = lds[t];
}

// ---------------- pass A: bucket-binned scatter (no coefficients yet) --------------
struct BinList { const int* dst; const int* srcp; const float* w; int shift; int* gcur; int2* tmp; };
struct BinArgs { BinList l[6]; };

__global__ __launch_bounds__(256) void k_binA(BinArgs ba) {
    const BinList L = ba.l[blockIdx.y];
    __shared__ int2 stg[CHUNK];
    __shared__ unsigned char bkt[CHUNK];
    __shared__ int hist[256], sbase[256], scur[256], gbase[256];
    const int t = threadIdx.x;
    const int e0 = blockIdx.x * CHUNK;
    const int ccnt = min(CHUNK, NE - e0);
    hist[t] = 0;
    __syncthreads();
#pragma unroll
    for (int j = 0; j < CHUNK / 256; ++j) {
        const int e = e0 + j * 256 + t;
        if (e < NE) atomicAdd(&hist[L.dst[e] >> L.shift], 1);
    }
    __syncthreads();
    {
        const int x = hist[t];
        sbase[t] = x;
        __syncthreads();
        for (int o = 1; o < 256; o <<= 1) {
            int add = (t >= o) ? sbase[t - o] : 0;
            __syncthreads();
            sbase[t] += add;
            __syncthreads();
        }
        const int excl = sbase[t] - x;
        __syncthreads();
        sbase[t] = excl;
        scur[t] = excl;
        gbase[t] = (x > 0) ? atomicAdd(&L.gcur[t], x) : 0;
    }
    __syncthreads();
#pragma unroll
    for (int j = 0; j < CHUNK / 256; ++j) {
        const int e = e0 + j * 256 + t;
        if (e < NE) {
            const int d = L.dst[e], s = L.srcp[e];
            const int b = d >> L.shift;
            const int p = atomicAdd(&scur[b], 1);
            stg[p] = make_int2(((d & ((1 << L.shift) - 1)) << 17) | s,
                               L.w ? __float_as_int(L.w[e]) : 0);
            bkt[p] = (unsigned char)b;
        }
    }
    __syncthreads();
    for (int i = t; i < ccnt; i += 256) {
        const int b = bkt[i];
        L.tmp[gbase[b] + (i - sbase[b])] = stg[i];
    }
}

// ---------------- per-bucket degree count + row starts (coalesced writes) ----------
struct DegArgs {
    const int2* tmp[6];
    const int* bstart;       // [6*257]
    int* rs[6];
    float* rdeg[6];
    int shift[6]; int n[6]; int bofs[7];
};

__global__ __launch_bounds__(256) void k_bdeg(DegArgs a) {
    __shared__ int cnt[512];
    __shared__ int lds[256];
    int l = 0;
    while ((int)blockIdx.x >= a.bofs[l + 1]) ++l;
    const int b = blockIdx.x - a.bofs[l];
    const int sh = a.shift[l], n = a.n[l];
    const int node0 = b << sh;
    const int node1 = min(node0 + (1 << sh), n);
    const int nn = node1 - node0;
    const int bs = a.bstart[l * 257 + b], be = a.bstart[l * 257 + b + 1];
    const int t = threadIdx.x;
    cnt[t] = 0; cnt[t + 256] = 0;
    __syncthreads();
    const int2* __restrict__ tmp = a.tmp[l];
    for (int i = bs + t; i < be; i += 256) atomicAdd(&cnt[((unsigned)tmp[i].x) >> 17], 1);
    __syncthreads();
    const int c0 = cnt[2 * t], c1 = cnt[2 * t + 1];
    lds[t] = c0 + c1;
    __syncthreads();
    for (int o = 1; o < 256; o <<= 1) {
        int add = (t >= o) ? lds[t - o] : 0;
        __syncthreads();
        lds[t] += add;
        __syncthreads();
    }
    const int ep = lds[t] - (c0 + c1);   // exclusive prefix at element 2t
    int* __restrict__ rs = a.rs[l];
    float* __restrict__ rd = a.rdeg[l];
    if (2 * t < nn) {
        rs[node0 + 2 * t] = bs + ep;
        rd[node0 + 2 * t] = rsqrtf((float)max(c0, 1));
    }
    if (2 * t + 1 < nn) {
        rs[node0 + 2 * t + 1] = bs + ep + c0;
        rd[node0 + 2 * t + 1] = rsqrtf((float)max(c1, 1));
    }
    if (t == 0) rs[node1] = be;
}

// ---------------- pass B: coefficient compute + exact row sort, coalesced ----------
// payload written as (src_byte_offset = src*256, coef)
struct SortArgs {
    const int2* tmp[6]; int2* outp[6];
    const int* rs[6];
    const float* rdD[6]; const float* rdS[6];
    const int* bstart;
    int shift[6]; int n[6]; int mode[6];   // mode 0: c  1: 0.5*w*c  2: 0.5*c
    int bofs[7];
};

__global__ __launch_bounds__(256) void k_binB(SortArgs a) {
    __shared__ int2 stg[STAGE_B];
    __shared__ int lcur[512];
    __shared__ float rdl[512];
    int l = 0;
    while ((int)blockIdx.x >= a.bofs[l + 1]) ++l;
    const int b = blockIdx.x - a.bofs[l];
    const int sh = a.shift[l], n = a.n[l], mode = a.mode[l];
    const int node0 = b << sh;
    const int node1 = min(node0 + (1 << sh), n);
    const int nn = node1 - node0;
    const int bs = a.bstart[l * 257 + b], be = a.bstart[l * 257 + b + 1], cnt = be - bs;
    const int t = threadIdx.x;
    const int* __restrict__ rs = a.rs[l];
    const float* __restrict__ rdD = a.rdD[l];
    for (int k = t; k < nn; k += 256) {
        lcur[k] = rs[node0 + k] - bs;
        rdl[k] = rdD[node0 + k];
    }
    __syncthreads();
    const int2* __restrict__ tmp = a.tmp[l];
    int2* __restrict__ outp = a.outp[l];
    const float* __restrict__ rdS = a.rdS[l];
    if (cnt <= STAGE_B) {
        for (int i = bs + t; i < be; i += 256) {
            const int2 v = tmp[i];
            const int dl = ((unsigned)v.x) >> 17, src = v.x & 0x1FFFF;
            float c = rdl[dl] * rdS[src];
            if (mode == 1) c *= 0.5f * __int_as_float(v.y);
            else if (mode == 2) c *= 0.5f;
            const int slot = atomicAdd(&lcur[dl], 1);
            stg[slot] = make_int2(src << 8, __float_as_int(c));
        }
        __syncthreads();
        for (int i = t; i < cnt; i += 256) outp[bs + i] = stg[i];
    } else {  // statistically unreachable fallback
        for (int i = bs + t; i < be; i += 256) {
            const int2 v = tmp[i];
            const int dl = ((unsigned)v.x) >> 17, src = v.x & 0x1FFFF;
            float c = rdl[dl] * rdS[src];
            if (mode == 1) c *= 0.5f * __int_as_float(v.y);
            else if (mode == 2) c *= 0.5f;
            const int slot = atomicAdd(&lcur[dl], 1);
            outp[bs + slot] = make_int2(src << 8, __float_as_int(c));
        }
    }
}

// ---------------- f32 -> bf16 convert (4 floats / thread) ----------------
__global__ void k_tobf16(const float* __restrict__ in, ushort* __restrict__ out, int n4) {
    int i = blockIdx.x * blockDim.x + threadIdx.x;
    if (i >= n4) return;
    float4 v = ((const float4*)in)[i];
    ((uint2*)out)[i] = make_uint2((f2bf(v.y) << 16) | f2bf(v.x),
                                  (f2bf(v.w) << 16) | f2bf(v.z));
}

// ---------------- side-partitioned conv: XCDs 0..XU-1 run side A, rest side B ------
// Each XCD owns a contiguous row chunk of its side -> its L2 caches ONE table only,
// and compulsory fill is table_size * (XCDs on that side) instead of *8.
struct ConvSide {
    const ushort* x;
    const int*  rs1; const int2* p1;
    const int*  rs2; const int2* p2;
    const ushort* base;
    float*  outf; float* outf2;
    ushort* outb;
    int n;
};

__device__ __forceinline__ void accum_list(const char* __restrict__ xb,
                                           const int* __restrict__ rs,
                                           const int2* __restrict__ p,
                                           int row, int laneb,
                                           float& ax, float& ay) {
    const int j0 = rs[row], j1 = rs[row + 1];
    const int lane = laneb >> 2;
    for (int jb = j0; jb < j1; jb += 64) {
        int2 mp = make_int2(0, 0);
        if (jb + lane < j1) mp = p[jb + lane];
        const int cnt = min(64, j1 - jb);
        int t = 0;
        for (; t + 8 <= cnt; t += 8) {
            unsigned v[8]; float c[8];
#pragma unroll
            for (int k = 0; k < 8; ++k) {
                const int so = __builtin_amdgcn_readlane(mp.x, t + k);
                c[k] = __int_as_float(__builtin_amdgcn_readlane(mp.y, t + k));
                v[k] = *(const unsigned*)(xb + so + laneb);
            }
#pragma unroll
            for (int k = 0; k < 8; ++k) {
                ax = fmaf(c[k], bflo(v[k]), ax);
                ay = fmaf(c[k], bfhi(v[k]), ay);
            }
        }
        if (t + 4 <= cnt) {
            unsigned v[4]; float c[4];
#pragma unroll
            for (int k = 0; k < 4; ++k) {
                const int so = __builtin_amdgcn_readlane(mp.x, t + k);
                c[k] = __int_as_float(__builtin_amdgcn_readlane(mp.y, t + k));
                v[k] = *(const unsigned*)(xb + so + laneb);
            }
#pragma unroll
            for (int k = 0; k < 4; ++k) {
                ax = fmaf(c[k], bflo(v[k]), ax);
                ay = fmaf(c[k], bfhi(v[k]), ay);
            }
            t += 4;
        }
        for (; t < cnt; ++t) {
            const int so = __builtin_amdgcn_readlane(mp.x, t);
            const float c = __int_as_float(__builtin_amdgcn_readlane(mp.y, t));
            const unsigned v = *(const unsigned*)(xb + so + laneb);
            ax = fmaf(c, bflo(v), ax);
            ay = fmaf(c, bfhi(v), ay);
        }
    }
}

#define XU 4   // XCDs for the user-dst side (item table); 8-XU for item-dst side

__global__ __launch_bounds__(256) void k_conv2x(ConvSide A, ConvSide B,
                                                int maxbA, int maxbB) {
    const int xcd = (int)blockIdx.x & 7;        // HW round-robin block->XCD mapping
    const int idx = (int)blockIdx.x >> 3;
    const ConvSide* S;
    int nch, chunk;
    if (xcd < XU) {
        if (idx >= maxbA) return;
        S = &A; nch = XU; chunk = xcd;
    } else {
        if (idx >= maxbB) return;
        S = &B; nch = 8 - XU; chunk = xcd - XU;
    }
    const int per = (S->n + nch - 1) / nch;     // rows per XCD chunk (contiguous)
    const int r0 = chunk * per;
    const int r1 = min(r0 + per, S->n);
    int row = r0 + idx * 4 + (int)(threadIdx.x >> 6);
    const int lane = threadIdx.x & 63;
    if (row >= r1) return;
    row = __builtin_amdgcn_readfirstlane(row);
    const int laneb = lane << 2;
    const size_t roff = (size_t)row * D + lane * 2;
    float ax = 0.f, ay = 0.f;
    if (S->base) {
        const unsigned b = *(const unsigned*)(S->base + roff);
        ax = bflo(b); ay = bfhi(b);
    }
    const char* xb = (const char*)S->x;
    accum_list(xb, S->rs1, S->p1, row, laneb, ax, ay);
    if (S->rs2) accum_list(xb, S->rs2, S->p2, row, laneb, ax, ay);
    if (S->outf)  *(float2*)(S->outf  + roff) = make_float2(ax, ay);
    if (S->outf2) *(float2*)(S->outf2 + roff) = make_float2(ax, ay);
    if (S->outb)  *(unsigned*)(S->outb + roff) = (f2bf(ay) << 16) | f2bf(ax);
}

extern "C" void kernel_launch(void* const* d_in, const int* in_sizes, int n_in,
                              void* d_out, int out_size, void* d_ws, size_t ws_size,
                              hipStream_t stream) {
    const float* user_emb = (const float*)d_in[0];
    const float* item_emb = (const float*)d_in[1];
    const float* w_edge   = (const float*)d_in[2];
    const int* ou = (const int*)d_in[3];
    const int* oi = (const int*)d_in[4];
    const int* su = (const int*)d_in[5];
    const int* si = (const int*)d_in[6];
    const int* du = (const int*)d_in[7];
    const int* di = (const int*)d_in[8];
    float* out = (float*)d_out;

    const size_t SZ_U = (size_t)N_USERS * D;
    const size_t SZ_I = (size_t)N_ITEMS * D;

    // output slices: (hu, hi, hu, hi, h1u, h1i)
    float* o0 = out;
    float* o1 = o0 + SZ_U;
    float* o2 = o1 + SZ_I;
    float* o3 = o2 + SZ_U;
    float* o4 = o3 + SZ_I;
    float* o5 = o4 + SZ_U;

    // bf16 intermediates live in the o4/o5 slices (dead until loop-2 iter2):
    ushort* tU0 = (ushort*)o4;  ushort* tU1 = tU0 + SZ_U;
    ushort* tI0 = (ushort*)o5;  ushort* tI1 = tI0 + SZ_I;

    // ---- workspace carve-out ----
    char* ws = (char*)d_ws;
    size_t off = 0;
    auto alloc = [&](size_t bytes) -> void* {
        void* p = ws + off;
        off = (off + bytes + 255) & ~(size_t)255;
        return p;
    };

    int* rOU = (int*)alloc((N_USERS + 1) * 4);
    int* rOI = (int*)alloc((N_ITEMS + 1) * 4);
    int* rSU = (int*)alloc((N_USERS + 1) * 4);
    int* rSI = (int*)alloc((N_ITEMS + 1) * 4);
    int* rDU = (int*)alloc((N_USERS + 1) * 4);
    int* rDI = (int*)alloc((N_ITEMS + 1) * 4);

    float* rdOU = (float*)alloc(N_USERS * 4);
    float* rdOI = (float*)alloc(N_ITEMS * 4);
    float* rdSU = (float*)alloc(N_USERS * 4);
    float* rdSI = (float*)alloc(N_ITEMS * 4);
    float* rdDU = (float*)alloc(N_USERS * 4);
    float* rdDI = (float*)alloc(N_ITEMS * 4);

    size_t bhBegin = off;
    int* bh     = (int*)alloc(6 * 256 * 4);
    size_t bhEnd = off;
    int* bstart = (int*)alloc(6 * 257 * 4);
    int* gcur   = (int*)alloc(6 * 256 * 4);

    int2* pOU = (int2*)alloc((size_t)NE * 8);
    int2* pOI = (int2*)alloc((size_t)NE * 8);
    int2* pSU = (int2*)alloc((size_t)NE * 8);
    int2* pSI = (int2*)alloc((size_t)NE * 8);
    int2* pDU = (int2*)alloc((size_t)NE * 8);
    int2* pDI = (int2*)alloc((size_t)NE * 8);

    int2* qOU = (int2*)alloc((size_t)NE * 8);   // binned (pass-A) staging
    int2* qOI = (int2*)alloc((size_t)NE * 8);
    int2* qSU = (int2*)alloc((size_t)NE * 8);
    int2* qSI = (int2*)alloc((size_t)NE * 8);
    int2* qDU = (int2*)alloc((size_t)NE * 8);
    int2* qDI = (int2*)alloc((size_t)NE * 8);

    ushort* ebU = (ushort*)alloc(SZ_U * 2);
    ushort* ebI = (ushort*)alloc(SZ_I * 2);
    ushort* fUb = (ushort*)alloc(SZ_U * 2);
    ushort* fIb = (ushort*)alloc(SZ_I * 2);

    // ---- phase 0: zero bucket hist; convert embeddings to bf16 ----
    hipMemsetAsync(ws + bhBegin, 0, bhEnd - bhBegin, stream);
    hipLaunchKernelGGL(k_tobf16, dim3((unsigned)(SZ_U / 4 + 255) / 256), dim3(256), 0, stream,
                       user_emb, ebU, (int)(SZ_U / 4));
    hipLaunchKernelGGL(k_tobf16, dim3((unsigned)(SZ_I / 4 + 255) / 256), dim3(256), 0, stream,
                       item_emb, ebI, (int)(SZ_I / 4));

    // ---- phase 1: bucket histograms + bucket scan ----
    HistArgs ha;
    ha.dst[0] = ou; ha.shift[0] = SH_U;
    ha.dst[1] = oi; ha.shift[1] = SH_I;
    ha.dst[2] = su; ha.shift[2] = SH_U;
    ha.dst[3] = si; ha.shift[3] = SH_I;
    ha.dst[4] = du; ha.shift[4] = SH_U;
    ha.dst[5] = di; ha.shift[5] = SH_I;
    ha.bh = bh;
    hipLaunchKernelGGL(k_bhist, dim3((NE + HCHUNK - 1) / HCHUNK, 6), dim3(256), 0, stream, ha);
    hipLaunchKernelGGL(k_scanB, dim3(6), dim3(256), 0, stream, bh, bstart, gcur);

    // ---- phase 2: pass A (bin by destination bucket) ----
    BinArgs ba;
    ba.l[0] = { ou, oi, nullptr, SH_U, gcur + 0 * 256, qOU };
    ba.l[1] = { oi, ou, nullptr, SH_I, gcur + 1 * 256, qOI };
    ba.l[2] = { su, si, w_edge,  SH_U, gcur + 2 * 256, qSU };
    ba.l[3] = { si, su, nullptr, SH_I, gcur + 3 * 256, qSI };
    ba.l[4] = { du, di, nullptr, SH_U, gcur + 4 * 256, qDU };
    ba.l[5] = { di, du, nullptr, SH_I, gcur + 5 * 256, qDI };
    hipLaunchKernelGGL(k_binA, dim3((NE + CHUNK - 1) / CHUNK, 6), dim3(256), 0, stream, ba);

    int bofs[7];
    {
        int nb[6] = { NB_U, NB_I, NB_U, NB_I, NB_U, NB_I };
        bofs[0] = 0;
        for (int i = 0; i < 6; ++i) bofs[i + 1] = bofs[i] + nb[i];
    }

    // ---- phase 3: per-bucket degrees + row starts ----
    DegArgs da;
    da.tmp[0] = qOU; da.rs[0] = rOU; da.rdeg[0] = rdOU; da.shift[0] = SH_U; da.n[0] = N_USERS;
    da.tmp[1] = qOI; da.rs[1] = rOI; da.rdeg[1] = rdOI; da.shift[1] = SH_I; da.n[1] = N_ITEMS;
    da.tmp[2] = qSU; da.rs[2] = rSU; da.rdeg[2] = rdSU; da.shift[2] = SH_U; da.n[2] = N_USERS;
    da.tmp[3] = qSI; da.rs[3] = rSI; da.rdeg[3] = rdSI; da.shift[3] = SH_I; da.n[3] = N_ITEMS;
    da.tmp[4] = qDU; da.rs[4] = rDU; da.rdeg[4] = rdDU; da.shift[4] = SH_U; da.n[4] = N_USERS;
    da.tmp[5] = qDI; da.rs[5] = rDI; da.rdeg[5] = rdDI; da.shift[5] = SH_I; da.n[5] = N_ITEMS;
    da.bstart = bstart;
    for (int i = 0; i < 7; ++i) da.bofs[i] = bofs[i];
    hipLaunchKernelGGL(k_bdeg, dim3(bofs[6]), dim3(256), 0, stream, da);

    // ---- phase 4: pass B (coefficients + exact row sort, src pre-scaled to bytes) --
    SortArgs so;
    so.tmp[0] = qOU; so.outp[0] = pOU; so.rs[0] = rOU; so.rdD[0] = rdOU; so.rdS[0] = rdOI;
    so.shift[0] = SH_U; so.n[0] = N_USERS; so.mode[0] = 0;
    so.tmp[1] = qOI; so.outp[1] = pOI; so.rs[1] = rOI; so.rdD[1] = rdOI; so.rdS[1] = rdOU;
    so.shift[1] = SH_I; so.n[1] = N_ITEMS; so.mode[1] = 0;
    so.tmp[2] = qSU; so.outp[2] = pSU; so.rs[2] = rSU; so.rdD[2] = rdSU; so.rdS[2] = rdSI;
    so.shift[2] = SH_U; so.n[2] = N_USERS; so.mode[2] = 1;
    so.tmp[3] = qSI; so.outp[3] = pSI; so.rs[3] = rSI; so.rdD[3] = rdSI; so.rdS[3] = rdSU;
    so.shift[3] = SH_I; so.n[3] = N_ITEMS; so.mode[3] = 2;
    so.tmp[4] = qDU; so.outp[4] = pDU; so.rs[4] = rDU; so.rdD[4] = rdDU; so.rdS[4] = rdDI;
    so.shift[4] = SH_U; so.n[4] = N_USERS; so.mode[4] = 0;
    so.tmp[5] = qDI; so.outp[5] = pDI; so.rs[5] = rDI; so.rdD[5] = rdDI; so.rdS[5] = rdDU;
    so.shift[5] = SH_I; so.n[5] = N_ITEMS; so.mode[5] = 0;
    so.bstart = bstart;
    for (int i = 0; i < 7; ++i) so.bofs[i] = bofs[i];
    hipLaunchKernelGGL(k_binB, dim3(bofs[6]), dim3(256), 0, stream, so);

    auto mkside = [](const ushort* x, const int* rs1, const int2* p1,
                     const int* rs2, const int2* p2, const ushort* base,
                     float* outf, float* outf2, ushort* outb, int n) {
        ConvSide s; s.x = x; s.rs1 = rs1; s.p1 = p1; s.rs2 = rs2; s.p2 = p2;
        s.base = base; s.outf = outf; s.outf2 = outf2; s.outb = outb; s.n = n;
        return s;
    };
    auto conv2x = [&](const ConvSide& A, const ConvSide& B) {
        const int perA = (A.n + XU - 1) / XU;
        const int perB = (B.n + (8 - XU) - 1) / (8 - XU);
        const int maxbA = (perA + 3) / 4;        // 4 rows (waves) per block
        const int maxbB = (perB + 3) / 4;
        const int nwg = 8 * max(maxbA, maxbB);
        hipLaunchKernelGGL(k_conv2x, dim3((unsigned)nwg), dim3(256), 0, stream,
                           A, B, maxbA, maxbB);
    };

    // ---- phase 5: loop 1 (3 layers); user side on XCD 0..3, item side on 4..7 ----
    conv2x(mkside(ebI, rOU, pOU, rSU, pSU, nullptr, nullptr, nullptr, tU0, N_USERS),
           mkside(ebU, rOI, pOI, rSI, pSI, nullptr, nullptr, nullptr, tI0, N_ITEMS));
    conv2x(mkside(tI0, rOU, pOU, rSU, pSU, nullptr, nullptr, nullptr, tU1, N_USERS),
           mkside(tU0, rOI, pOI, rSI, pSI, nullptr, nullptr, nullptr, tI1, N_ITEMS));
    conv2x(mkside(tI1, rOU, pOU, rSU, pSU, nullptr, o0, o2, tU0, N_USERS),
           mkside(tU1, rOI, pOI, rSI, pSI, nullptr, o1, o3, tI0, N_ITEMS));

    // ---- phase 6: constant seek terms from bf16 finals; coefs include the 0.5 ----
    conv2x(mkside(tI0, rSU, pSU, nullptr, nullptr, nullptr, nullptr, nullptr, fUb, N_USERS),
           mkside(tU0, rSI, pSI, nullptr, nullptr, nullptr, nullptr, nullptr, fIb, N_ITEMS));

    // ---- phase 7: loop 2 (3 layers), dn graph + constant bf16 base ----
    conv2x(mkside(ebI, rDU, pDU, nullptr, nullptr, fUb, nullptr, nullptr, tU1, N_USERS),
           mkside(ebU, rDI, pDI, nullptr, nullptr, fIb, nullptr, nullptr, tI1, N_ITEMS));
    conv2x(mkside(tI1, rDU, pDU, nullptr, nullptr, fUb, nullptr, nullptr, ebU, N_USERS),
           mkside(tU1, rDI, pDI, nullptr, nullptr, fIb, nullptr, nullptr, ebI, N_ITEMS));
    conv2x(mkside(ebI, rDU, pDU, nullptr, nullptr, fUb, o4, nullptr, nullptr, N_USERS),
           mkside(ebU, rDI, pDI, nullptr, nullptr, fIb, o5, nullptr, nullptr, N_ITEMS));
}

// Round 12
// 835.393 us; speedup vs baseline: 1.6200x; 1.1464x over previous
//
#include <hip/hip_runtime.h>

#define N_USERS 100000
#define N_ITEMS 30000
#define NE      1000000
#define D       128
#define CHUNK   4096
#define HCHUNK  8192
#define STAGE_B 7424
#define SH_U    9    // 512 users/bucket  -> 196 buckets
#define SH_I    7    // 128 items/bucket  -> 235 buckets
#define NB_U    ((N_USERS + (1 << SH_U) - 1) >> SH_U)
#define NB_I    ((N_ITEMS + (1 << SH_I) - 1) >> SH_I)

__device__ __forceinline__ unsigned f2bf(float f) {
    unsigned u = __float_as_uint(f);
    return (u + 0x7fffu + ((u >> 16) & 1u)) >> 16;   // RNE, no NaN expected
}
__device__ __forceinline__ float bflo(unsigned v) { return __uint_as_float(v << 16); }
__device__ __forceinline__ float bfhi(unsigned v) { return __uint_as_float(v & 0xffff0000u); }

// ---------------- bucket histograms (LDS-aggregated, tiny global atomics) ----------
struct HistArgs { const int* dst[6]; int shift[6]; int* bh; };

__global__ __launch_bounds__(256) void k_bhist(HistArgs a) {
    __shared__ int h[256];
    const int l = blockIdx.y;
    const int* __restrict__ dst = a.dst[l];
    const int sh = a.shift[l];
    const int t = threadIdx.x;
    h[t] = 0;
    __syncthreads();
    const int e0 = blockIdx.x * HCHUNK;
    const int e1 = min(e0 + HCHUNK, NE);
    for (int e = e0 + t; e < e1; e += 256) atomicAdd(&h[dst[e] >> sh], 1);
    __syncthreads();
    if (h[t]) atomicAdd(&a.bh[l * 256 + t], h[t]);
}

// ---------------- bucket-count scan: bucket starts + pass-A cursors ----------------
__global__ void k_scanB(const int* __restrict__ bh, int* __restrict__ bstart,
                        int* __restrict__ gcur) {
    __shared__ int lds[256];
    const int l = blockIdx.x, t = threadIdx.x;
    const int x = bh[l * 256 + t];
    lds[t] = x;
    __syncthreads();
    for (int o = 1; o < 256; o <<= 1) {
        int add = (t >= o) ? lds[t - o] : 0;
        __syncthreads();
        lds[t] += add;
        __syncthreads();
    }
    const int excl = lds[t] - x;
    bstart[l * 257 + t] = excl;
    gcur[l * 256 + t] = excl;
    if (t == 255) bstart[l * 257 + 256] = lds[t];
}

// ---------------- pass A: bucket-binned scatter (no coefficients yet) --------------
struct BinList { const int* dst; const int* srcp; const float* w; int shift; int* gcur; int2* tmp; };
struct BinArgs { BinList l[6]; };

__global__ __launch_bounds__(256) void k_binA(BinArgs ba) {
    const BinList L = ba.l[blockIdx.y];
    __shared__ int2 stg[CHUNK];
    __shared__ unsigned char bkt[CHUNK];
    __shared__ int hist[256], sbase[256], scur[256], gbase[256];
    const int t = threadIdx.x;
    const int e0 = blockIdx.x * CHUNK;
    const int ccnt = min(CHUNK, NE - e0);
    hist[t] = 0;
    __syncthreads();
#pragma unroll
    for (int j = 0; j < CHUNK / 256; ++j) {
        const int e = e0 + j * 256 + t;
        if (e < NE) atomicAdd(&hist[L.dst[e] >> L.shift], 1);
    }
    __syncthreads();
    {
        const int x = hist[t];
        sbase[t] = x;
        __syncthreads();
        for (int o = 1; o < 256; o <<= 1) {
            int add = (t >= o) ? sbase[t - o] : 0;
            __syncthreads();
            sbase[t] += add;
            __syncthreads();
        }
        const int excl = sbase[t] - x;
        __syncthreads();
        sbase[t] = excl;
        scur[t] = excl;
        gbase[t] = (x > 0) ? atomicAdd(&L.gcur[t], x) : 0;
    }
    __syncthreads();
#pragma unroll
    for (int j = 0; j < CHUNK / 256; ++j) {
        const int e = e0 + j * 256 + t;
        if (e < NE) {
            const int d = L.dst[e], s = L.srcp[e];
            const int b = d >> L.shift;
            const int p = atomicAdd(&scur[b], 1);
            stg[p] = make_int2(((d & ((1 << L.shift) - 1)) << 17) | s,
                               L.w ? __float_as_int(L.w[e]) : 0);
            bkt[p] = (unsigned char)b;
        }
    }
    __syncthreads();
    for (int i = t; i < ccnt; i += 256) {
        const int b = bkt[i];
        L.tmp[gbase[b] + (i - sbase[b])] = stg[i];
    }
}

// ---------------- per-bucket degree count + row starts (coalesced writes) ----------
struct DegArgs {
    const int2* tmp[6];
    const int* bstart;       // [6*257]
    int* rs[6];
    float* rdeg[6];
    int shift[6]; int n[6]; int bofs[7];
};

__global__ __launch_bounds__(256) void k_bdeg(DegArgs a) {
    __shared__ int cnt[512];
    __shared__ int lds[256];
    int l = 0;
    while ((int)blockIdx.x >= a.bofs[l + 1]) ++l;
    const int b = blockIdx.x - a.bofs[l];
    const int sh = a.shift[l], n = a.n[l];
    const int node0 = b << sh;
    const int node1 = min(node0 + (1 << sh), n);
    const int nn = node1 - node0;
    const int bs = a.bstart[l * 257 + b], be = a.bstart[l * 257 + b + 1];
    const int t = threadIdx.x;
    cnt[t] = 0; cnt[t + 256] = 0;
    __syncthreads();
    const int2* __restrict__ tmp = a.tmp[l];
    for (int i = bs + t; i < be; i += 256) atomicAdd(&cnt[((unsigned)tmp[i].x) >> 17], 1);
    __syncthreads();
    const int c0 = cnt[2 * t], c1 = cnt[2 * t + 1];
    lds[t] = c0 + c1;
    __syncthreads();
    for (int o = 1; o < 256; o <<= 1) {
        int add = (t >= o) ? lds[t - o] : 0;
        __syncthreads();
        lds[t] += add;
        __syncthreads();
    }
    const int ep = lds[t] - (c0 + c1);   // exclusive prefix at element 2t
    int* __restrict__ rs = a.rs[l];
    float* __restrict__ rd = a.rdeg[l];
    if (2 * t < nn) {
        rs[node0 + 2 * t] = bs + ep;
        rd[node0 + 2 * t] = rsqrtf((float)max(c0, 1));
    }
    if (2 * t + 1 < nn) {
        rs[node0 + 2 * t + 1] = bs + ep + c0;
        rd[node0 + 2 * t + 1] = rsqrtf((float)max(c1, 1));
    }
    if (t == 0) rs[node1] = be;
}

// ---------------- pass B: coefficient compute + exact row sort, coalesced ----------
// payload written as (src_byte_offset = src*256, coef)
struct SortArgs {
    const int2* tmp[6]; int2* outp[6];
    const int* rs[6];
    const float* rdD[6]; const float* rdS[6];
    const int* bstart;
    int shift[6]; int n[6]; int mode[6];   // mode 0: c  1: 0.5*w*c  2: 0.5*c
    int bofs[7];
};

__global__ __launch_bounds__(256) void k_binB(SortArgs a) {
    __shared__ int2 stg[STAGE_B];
    __shared__ int lcur[512];
    __shared__ float rdl[512];
    int l = 0;
    while ((int)blockIdx.x >= a.bofs[l + 1]) ++l;
    const int b = blockIdx.x - a.bofs[l];
    const int sh = a.shift[l], n = a.n[l], mode = a.mode[l];
    const int node0 = b << sh;
    const int node1 = min(node0 + (1 << sh), n);
    const int nn = node1 - node0;
    const int bs = a.bstart[l * 257 + b], be = a.bstart[l * 257 + b + 1], cnt = be - bs;
    const int t = threadIdx.x;
    const int* __restrict__ rs = a.rs[l];
    const float* __restrict__ rdD = a.rdD[l];
    for (int k = t; k < nn; k += 256) {
        lcur[k] = rs[node0 + k] - bs;
        rdl[k] = rdD[node0 + k];
    }
    __syncthreads();
    const int2* __restrict__ tmp = a.tmp[l];
    int2* __restrict__ outp = a.outp[l];
    const float* __restrict__ rdS = a.rdS[l];
    if (cnt <= STAGE_B) {
        for (int i = bs + t; i < be; i += 256) {
            const int2 v = tmp[i];
            const int dl = ((unsigned)v.x) >> 17, src = v.x & 0x1FFFF;
            float c = rdl[dl] * rdS[src];
            if (mode == 1) c *= 0.5f * __int_as_float(v.y);
            else if (mode == 2) c *= 0.5f;
            const int slot = atomicAdd(&lcur[dl], 1);
            stg[slot] = make_int2(src << 8, __float_as_int(c));
        }
        __syncthreads();
        for (int i = t; i < cnt; i += 256) outp[bs + i] = stg[i];
    } else {  // statistically unreachable fallback
        for (int i = bs + t; i < be; i += 256) {
            const int2 v = tmp[i];
            const int dl = ((unsigned)v.x) >> 17, src = v.x & 0x1FFFF;
            float c = rdl[dl] * rdS[src];
            if (mode == 1) c *= 0.5f * __int_as_float(v.y);
            else if (mode == 2) c *= 0.5f;
            const int slot = atomicAdd(&lcur[dl], 1);
            outp[bs + slot] = make_int2(src << 8, __float_as_int(c));
        }
    }
}

// ---------------- f32 -> bf16 convert (4 floats / thread) ----------------
__global__ void k_tobf16(const float* __restrict__ in, ushort* __restrict__ out, int n4) {
    int i = blockIdx.x * blockDim.x + threadIdx.x;
    if (i >= n4) return;
    float4 v = ((const float4*)in)[i];
    ((uint2*)out)[i] = make_uint2((f2bf(v.y) << 16) | f2bf(v.x),
                                  (f2bf(v.w) << 16) | f2bf(v.z));
}

// ---------------- single-side conv (cache-pure gather stream, XCD swizzle) ----------
struct ConvSide {
    const ushort* x;
    const int*  rs1; const int2* p1;
    const int*  rs2; const int2* p2;
    const ushort* base;
    float*  outf; float* outf2;
    ushort* outb;
    int n;
};

__device__ __forceinline__ void accum_list(const char* __restrict__ xb,
                                           const int* __restrict__ rs,
                                           const int2* __restrict__ p,
                                           int row, int laneb,
                                           float& ax, float& ay) {
    const int j0 = rs[row], j1 = rs[row + 1];
    const int lane = laneb >> 2;
    for (int jb = j0; jb < j1; jb += 64) {
        int2 mp = make_int2(0, 0);
        if (jb + lane < j1) mp = p[jb + lane];
        const int cnt = min(64, j1 - jb);
        int t = 0;
        for (; t + 8 <= cnt; t += 8) {
            unsigned v[8]; float c[8];
#pragma unroll
            for (int k = 0; k < 8; ++k) {
                const int so = __builtin_amdgcn_readlane(mp.x, t + k);
                c[k] = __int_as_float(__builtin_amdgcn_readlane(mp.y, t + k));
                v[k] = *(const unsigned*)(xb + so + laneb);
            }
#pragma unroll
            for (int k = 0; k < 8; ++k) {
                ax = fmaf(c[k], bflo(v[k]), ax);
                ay = fmaf(c[k], bfhi(v[k]), ay);
            }
        }
        if (t + 4 <= cnt) {
            unsigned v[4]; float c[4];
#pragma unroll
            for (int k = 0; k < 4; ++k) {
                const int so = __builtin_amdgcn_readlane(mp.x, t + k);
                c[k] = __int_as_float(__builtin_amdgcn_readlane(mp.y, t + k));
                v[k] = *(const unsigned*)(xb + so + laneb);
            }
#pragma unroll
            for (int k = 0; k < 4; ++k) {
                ax = fmaf(c[k], bflo(v[k]), ax);
                ay = fmaf(c[k], bfhi(v[k]), ay);
            }
            t += 4;
        }
        for (; t < cnt; ++t) {
            const int so = __builtin_amdgcn_readlane(mp.x, t);
            const float c = __int_as_float(__builtin_amdgcn_readlane(mp.y, t));
            const unsigned v = *(const unsigned*)(xb + so + laneb);
            ax = fmaf(c, bflo(v), ax);
            ay = fmaf(c, bfhi(v), ay);
        }
    }
}

__global__ void k_conv1(ConvSide S) {
    // bijective XCD swizzle: gridDim.x is a multiple of 8; each XCD gets a
    // contiguous row range -> neighbor rows (shared src lines) co-located on one L2.
    const int q = (int)gridDim.x >> 3;
    const int bid = (int)blockIdx.x;
    const int rb = (bid & 7) * q + (bid >> 3);
    int row = rb * 4 + (int)(threadIdx.x >> 6);
    const int lane = threadIdx.x & 63;
    if (row >= S.n) return;
    row = __builtin_amdgcn_readfirstlane(row);
    const int laneb = lane << 2;
    const size_t roff = (size_t)row * D + lane * 2;
    float ax = 0.f, ay = 0.f;
    if (S.base) {
        const unsigned b = *(const unsigned*)(S.base + roff);
        ax = bflo(b); ay = bfhi(b);
    }
    const char* xb = (const char*)S.x;
    accum_list(xb, S.rs1, S.p1, row, laneb, ax, ay);
    if (S.rs2) accum_list(xb, S.rs2, S.p2, row, laneb, ax, ay);
    if (S.outf)  *(float2*)(S.outf  + roff) = make_float2(ax, ay);
    if (S.outf2) *(float2*)(S.outf2 + roff) = make_float2(ax, ay);
    if (S.outb)  *(unsigned*)(S.outb + roff) = (f2bf(ay) << 16) | f2bf(ax);
}

extern "C" void kernel_launch(void* const* d_in, const int* in_sizes, int n_in,
                              void* d_out, int out_size, void* d_ws, size_t ws_size,
                              hipStream_t stream) {
    const float* user_emb = (const float*)d_in[0];
    const float* item_emb = (const float*)d_in[1];
    const float* w_edge   = (const float*)d_in[2];
    const int* ou = (const int*)d_in[3];
    const int* oi = (const int*)d_in[4];
    const int* su = (const int*)d_in[5];
    const int* si = (const int*)d_in[6];
    const int* du = (const int*)d_in[7];
    const int* di = (const int*)d_in[8];
    float* out = (float*)d_out;

    const size_t SZ_U = (size_t)N_USERS * D;
    const size_t SZ_I = (size_t)N_ITEMS * D;

    // output slices: (hu, hi, hu, hi, h1u, h1i)
    float* o0 = out;
    float* o1 = o0 + SZ_U;
    float* o2 = o1 + SZ_I;
    float* o3 = o2 + SZ_U;
    float* o4 = o3 + SZ_I;
    float* o5 = o4 + SZ_U;

    // bf16 intermediates live in the o4/o5 slices (dead until loop-2 iter2):
    ushort* tU0 = (ushort*)o4;  ushort* tU1 = tU0 + SZ_U;
    ushort* tI0 = (ushort*)o5;  ushort* tI1 = tI0 + SZ_I;

    // ---- workspace carve-out ----
    char* ws = (char*)d_ws;
    size_t off = 0;
    auto alloc = [&](size_t bytes) -> void* {
        void* p = ws + off;
        off = (off + bytes + 255) & ~(size_t)255;
        return p;
    };

    int* rOU = (int*)alloc((N_USERS + 1) * 4);
    int* rOI = (int*)alloc((N_ITEMS + 1) * 4);
    int* rSU = (int*)alloc((N_USERS + 1) * 4);
    int* rSI = (int*)alloc((N_ITEMS + 1) * 4);
    int* rDU = (int*)alloc((N_USERS + 1) * 4);
    int* rDI = (int*)alloc((N_ITEMS + 1) * 4);

    float* rdOU = (float*)alloc(N_USERS * 4);
    float* rdOI = (float*)alloc(N_ITEMS * 4);
    float* rdSU = (float*)alloc(N_USERS * 4);
    float* rdSI = (float*)alloc(N_ITEMS * 4);
    float* rdDU = (float*)alloc(N_USERS * 4);
    float* rdDI = (float*)alloc(N_ITEMS * 4);

    size_t bhBegin = off;
    int* bh     = (int*)alloc(6 * 256 * 4);
    size_t bhEnd = off;
    int* bstart = (int*)alloc(6 * 257 * 4);
    int* gcur   = (int*)alloc(6 * 256 * 4);

    int2* pOU = (int2*)alloc((size_t)NE * 8);
    int2* pOI = (int2*)alloc((size_t)NE * 8);
    int2* pSU = (int2*)alloc((size_t)NE * 8);
    int2* pSI = (int2*)alloc((size_t)NE * 8);
    int2* pDU = (int2*)alloc((size_t)NE * 8);
    int2* pDI = (int2*)alloc((size_t)NE * 8);

    int2* qOU = (int2*)alloc((size_t)NE * 8);   // binned (pass-A) staging
    int2* qOI = (int2*)alloc((size_t)NE * 8);
    int2* qSU = (int2*)alloc((size_t)NE * 8);
    int2* qSI = (int2*)alloc((size_t)NE * 8);
    int2* qDU = (int2*)alloc((size_t)NE * 8);
    int2* qDI = (int2*)alloc((size_t)NE * 8);

    ushort* ebU = (ushort*)alloc(SZ_U * 2);
    ushort* ebI = (ushort*)alloc(SZ_I * 2);
    ushort* fUb = (ushort*)alloc(SZ_U * 2);
    ushort* fIb = (ushort*)alloc(SZ_I * 2);

    // ---- phase 0: zero bucket hist; convert embeddings to bf16 ----
    hipMemsetAsync(ws + bhBegin, 0, bhEnd - bhBegin, stream);
    hipLaunchKernelGGL(k_tobf16, dim3((unsigned)(SZ_U / 4 + 255) / 256), dim3(256), 0, stream,
                       user_emb, ebU, (int)(SZ_U / 4));
    hipLaunchKernelGGL(k_tobf16, dim3((unsigned)(SZ_I / 4 + 255) / 256), dim3(256), 0, stream,
                       item_emb, ebI, (int)(SZ_I / 4));

    // ---- phase 1: bucket histograms + bucket scan ----
    HistArgs ha;
    ha.dst[0] = ou; ha.shift[0] = SH_U;
    ha.dst[1] = oi; ha.shift[1] = SH_I;
    ha.dst[2] = su; ha.shift[2] = SH_U;
    ha.dst[3] = si; ha.shift[3] = SH_I;
    ha.dst[4] = du; ha.shift[4] = SH_U;
    ha.dst[5] = di; ha.shift[5] = SH_I;
    ha.bh = bh;
    hipLaunchKernelGGL(k_bhist, dim3((NE + HCHUNK - 1) / HCHUNK, 6), dim3(256), 0, stream, ha);
    hipLaunchKernelGGL(k_scanB, dim3(6), dim3(256), 0, stream, bh, bstart, gcur);

    // ---- phase 2: pass A (bin by destination bucket) ----
    BinArgs ba;
    ba.l[0] = { ou, oi, nullptr, SH_U, gcur + 0 * 256, qOU };
    ba.l[1] = { oi, ou, nullptr, SH_I, gcur + 1 * 256, qOI };
    ba.l[2] = { su, si, w_edge,  SH_U, gcur + 2 * 256, qSU };
    ba.l[3] = { si, su, nullptr, SH_I, gcur + 3 * 256, qSI };
    ba.l[4] = { du, di, nullptr, SH_U, gcur + 4 * 256, qDU };
    ba.l[5] = { di, du, nullptr, SH_I, gcur + 5 * 256, qDI };
    hipLaunchKernelGGL(k_binA, dim3((NE + CHUNK - 1) / CHUNK, 6), dim3(256), 0, stream, ba);

    int bofs[7];
    {
        int nb[6] = { NB_U, NB_I, NB_U, NB_I, NB_U, NB_I };
        bofs[0] = 0;
        for (int i = 0; i < 6; ++i) bofs[i + 1] = bofs[i] + nb[i];
    }

    // ---- phase 3: per-bucket degrees + row starts ----
    DegArgs da;
    da.tmp[0] = qOU; da.rs[0] = rOU; da.rdeg[0] = rdOU; da.shift[0] = SH_U; da.n[0] = N_USERS;
    da.tmp[1] = qOI; da.rs[1] = rOI; da.rdeg[1] = rdOI; da.shift[1] = SH_I; da.n[1] = N_ITEMS;
    da.tmp[2] = qSU; da.rs[2] = rSU; da.rdeg[2] = rdSU; da.shift[2] = SH_U; da.n[2] = N_USERS;
    da.tmp[3] = qSI; da.rs[3] = rSI; da.rdeg[3] = rdSI; da.shift[3] = SH_I; da.n[3] = N_ITEMS;
    da.tmp[4] = qDU; da.rs[4] = rDU; da.rdeg[4] = rdDU; da.shift[4] = SH_U; da.n[4] = N_USERS;
    da.tmp[5] = qDI; da.rs[5] = rDI; da.rdeg[5] = rdDI; da.shift[5] = SH_I; da.n[5] = N_ITEMS;
    da.bstart = bstart;
    for (int i = 0; i < 7; ++i) da.bofs[i] = bofs[i];
    hipLaunchKernelGGL(k_bdeg, dim3(bofs[6]), dim3(256), 0, stream, da);

    // ---- phase 4: pass B (coefficients + exact row sort, src pre-scaled to bytes) --
    SortArgs so;
    so.tmp[0] = qOU; so.outp[0] = pOU; so.rs[0] = rOU; so.rdD[0] = rdOU; so.rdS[0] = rdOI;
    so.shift[0] = SH_U; so.n[0] = N_USERS; so.mode[0] = 0;
    so.tmp[1] = qOI; so.outp[1] = pOI; so.rs[1] = rOI; so.rdD[1] = rdOI; so.rdS[1] = rdOU;
    so.shift[1] = SH_I; so.n[1] = N_ITEMS; so.mode[1] = 0;
    so.tmp[2] = qSU; so.outp[2] = pSU; so.rs[2] = rSU; so.rdD[2] = rdSU; so.rdS[2] = rdSI;
    so.shift[2] = SH_U; so.n[2] = N_USERS; so.mode[2] = 1;
    so.tmp[3] = qSI; so.outp[3] = pSI; so.rs[3] = rSI; so.rdD[3] = rdSI; so.rdS[3] = rdSU;
    so.shift[3] = SH_I; so.n[3] = N_ITEMS; so.mode[3] = 2;
    so.tmp[4] = qDU; so.outp[4] = pDU; so.rs[4] = rDU; so.rdD[4] = rdDU; so.rdS[4] = rdDI;
    so.shift[4] = SH_U; so.n[4] = N_USERS; so.mode[4] = 0;
    so.tmp[5] = qDI; so.outp[5] = pDI; so.rs[5] = rDI; so.rdD[5] = rdDI; so.rdS[5] = rdDU;
    so.shift[5] = SH_I; so.n[5] = N_ITEMS; so.mode[5] = 0;
    so.bstart = bstart;
    for (int i = 0; i < 7; ++i) so.bofs[i] = bofs[i];
    hipLaunchKernelGGL(k_binB, dim3(bofs[6]), dim3(256), 0, stream, so);

    auto mkside = [](const ushort* x, const int* rs1, const int2* p1,
                     const int* rs2, const int2* p2, const ushort* base,
                     float* outf, float* outf2, ushort* outb, int n) {
        ConvSide s; s.x = x; s.rs1 = rs1; s.p1 = p1; s.rs2 = rs2; s.p2 = p2;
        s.base = base; s.outf = outf; s.outf2 = outf2; s.outb = outb; s.n = n;
        return s;
    };
    auto conv1 = [&](const ConvSide& S) {
        const int nb = (S.n + 3) / 4;
        const int nwg = (nb + 7) & ~7;         // pad to multiple of 8 for swizzle
        hipLaunchKernelGGL(k_conv1, dim3((unsigned)nwg), dim3(256), 0, stream, S);
    };

    // ---- phase 5: loop 1 (3 layers); one dispatch per side (cache purity) ----
    conv1(mkside(ebI, rOU, pOU, rSU, pSU, nullptr, nullptr, nullptr, tU0, N_USERS));
    conv1(mkside(ebU, rOI, pOI, rSI, pSI, nullptr, nullptr, nullptr, tI0, N_ITEMS));
    conv1(mkside(tI0, rOU, pOU, rSU, pSU, nullptr, nullptr, nullptr, tU1, N_USERS));
    conv1(mkside(tU0, rOI, pOI, rSI, pSI, nullptr, nullptr, nullptr, tI1, N_ITEMS));
    conv1(mkside(tI1, rOU, pOU, rSU, pSU, nullptr, o0, o2, tU0, N_USERS));
    conv1(mkside(tU1, rOI, pOI, rSI, pSI, nullptr, o1, o3, tI0, N_ITEMS));

    // ---- phase 6: constant seek terms from bf16 finals; coefs include the 0.5 ----
    conv1(mkside(tI0, rSU, pSU, nullptr, nullptr, nullptr, nullptr, nullptr, fUb, N_USERS));
    conv1(mkside(tU0, rSI, pSI, nullptr, nullptr, nullptr, nullptr, nullptr, fIb, N_ITEMS));

    // ---- phase 7: loop 2 (3 layers), dn graph + constant bf16 base ----
    conv1(mkside(ebI, rDU, pDU, nullptr, nullptr, fUb, nullptr, nullptr, tU1, N_USERS));
    conv1(mkside(ebU, rDI, pDI, nullptr, nullptr, fIb, nullptr, nullptr, tI1, N_ITEMS));
    conv1(mkside(tI1, rDU, pDU, nullptr, nullptr, fUb, nullptr, nullptr, ebU, N_USERS));
    conv1(mkside(tU1, rDI, pDI, nullptr, nullptr, fIb, nullptr, nullptr, ebI, N_ITEMS));
    conv1(mkside(ebI, rDU, pDU, nullptr, nullptr, fUb, o4, nullptr, nullptr, N_USERS));
    conv1(mkside(ebU, rDI, pDI, nullptr, nullptr, fIb, o5, nullptr, nullptr, N_ITEMS));
}